// Round 10
// baseline (304.792 us; speedup 1.0000x reference)
//
#include <hip/hip_runtime.h>
#include <hip/hip_bf16.h>
#include <stdint.h>

// Problem constants
#define B_ 64
#define T_ 512
#define H_ 256
#define D_ 512
#define MS_ 64
#define ML_ 8
#define NST_ 64

typedef unsigned short u16;
typedef __bf16 bf8 __attribute__((ext_vector_type(8)));
typedef float f4 __attribute__((ext_vector_type(4)));

__device__ __forceinline__ u16 f2bf(float f) {
    unsigned u = __builtin_bit_cast(unsigned, f);
    u += 0x7fffu + ((u >> 16) & 1u);   // round-to-nearest-even
    return (u16)(u >> 16);
}
__device__ __forceinline__ float bf2f(u16 v) {
    return __builtin_bit_cast(float, (unsigned)v << 16);
}
__device__ __forceinline__ float sigm(float x) { return 1.f / (1.f + __expf(-x)); }

// NOTE: LDS tiles MUST be standalone __shared__ arrays (16B-aligned), not
// struct members. struct SB (align 4) defeated b128 LDS vectorization:
// conflicts 5.3e6 -> 4.5e7, xgate 48us -> 117us (rounds 5-8 regression).

// ---------------- pack_spans (1 block/sentence, 1 thread/token) -------------
__global__ __launch_bounds__(512) void pack_spans2(const int* __restrict__ bio,
                                                   int* __restrict__ tok,
                                                   int* __restrict__ lenb) {
    __shared__ int wsum[8];
    __shared__ int start_s[64];
    __shared__ int len_s[64];
    int b = blockIdx.x;
    int t = threadIdx.x;
    int lane = t & 63, w = t >> 6;
    int v = bio[b * T_ + t];
    int bm = (v == 1);
    int im = (v == 2);
    if (t < 64) len_s[t] = 0;

    int x = bm;
#pragma unroll
    for (int off = 1; off < 64; off <<= 1) {
        int y = __shfl_up(x, off, 64);
        if (lane >= off) x += y;
    }
    if (lane == 63) wsum[w] = x;
    __syncthreads();
    int wof = 0;
    for (int i = 0; i < w; ++i) wof += wsum[i];
    int sid = x + wof - 1;
    int valid = ((bm | im) && sid >= 0) ? 1 : 0;
    __syncthreads();

    x = valid;
#pragma unroll
    for (int off = 1; off < 64; off <<= 1) {
        int y = __shfl_up(x, off, 64);
        if (lane >= off) x += y;
    }
    if (lane == 63) wsum[w] = x;
    __syncthreads();
    wof = 0;
    for (int i = 0; i < w; ++i) wof += wsum[i];
    int cs = x + wof;

    if (bm && sid < MS_) start_s[sid] = cs;
    __syncthreads();

    if (valid && sid < MS_) {
        int rank = cs - start_s[sid];
        if (rank < ML_) {
            tok[(b * MS_ + sid) * ML_ + rank] = t;
            atomicAdd(&len_s[sid], 1);
        }
    }
    __syncthreads();
    if (t < 64) lenb[b * MS_ + t] = len_s[t];
}

// ---------------- prep: block0 = lists; others = weight reorder + gather ----
// Gate-interleaved column reorder: col n: gate = (n&63)>>4, j = (n>>6)*16+(n&15),
// orig_row = gate*256 + j.  wcx[dir][n][0:512], wch[dir][n][0:256], bc[dir][n].
__global__ __launch_bounds__(256) void prep(
        const float* __restrict__ wihf, const float* __restrict__ whhf,
        const float* __restrict__ wihb, const float* __restrict__ whhb,
        const float* __restrict__ bf, const float* __restrict__ bb,
        u16* __restrict__ wcx, u16* __restrict__ wch, float* __restrict__ bc,
        const float* __restrict__ repr, const int* __restrict__ tok,
        const int* __restrict__ lenb,
        int* __restrict__ lists, int* __restrict__ counts, u16* __restrict__ xg) {
    int bid = blockIdx.x, gsz = gridDim.x, tid = threadIdx.x;
    if (bid == 0) {
        // per-step compacted active-span lists; counts[p] = #spans with len > p
        __shared__ int wsum[4];
        int lane = tid & 63, w = tid >> 6;
        int len[16];
#pragma unroll
        for (int i = 0; i < 16; ++i) len[i] = lenb[tid * 16 + i];
        for (int p = 0; p < ML_; ++p) {
            int c = 0;
#pragma unroll
            for (int i = 0; i < 16; ++i) c += (len[i] > p) ? 1 : 0;
            int x = c;
#pragma unroll
            for (int off = 1; off < 64; off <<= 1) {
                int y = __shfl_up(x, off, 64);
                if (lane >= off) x += y;
            }
            if (lane == 63) wsum[w] = x;
            __syncthreads();
            int wof = 0;
            for (int i = 0; i < w; ++i) wof += wsum[i];
            int pos = wof + x - c;
#pragma unroll
            for (int i = 0; i < 16; ++i)
                if (len[i] > p) lists[p * 4096 + pos++] = tid * 16 + i;
            if (tid == 255) counts[p] = pos;
            __syncthreads();
        }
        return;
    }
    int b1 = bid - 1, g1 = gsz - 1;
    // weight reorder: 6152 chunks x 256 elems (2*1024*768 weights + 2048 bias)
    for (int ch = b1; ch < 6152; ch += g1) {
        int i = ch * 256 + tid;
        if (i < 1572864) {
            int dir = i / 786432;
            int rem = i - dir * 786432;
            int n = rem / 768;
            int k = rem - n * 768;
            int nn = n & 63, c = n >> 6;
            int orig = (nn >> 4) * 256 + c * 16 + (nn & 15);
            if (k < 512) {
                const float* wih = dir ? wihb : wihf;
                wcx[((size_t)dir * 1024 + n) * 512 + k] = f2bf(wih[orig * 512 + k]);
            } else {
                const float* whh = dir ? whhb : whhf;
                wch[((size_t)dir * 1024 + n) * 256 + (k - 512)] =
                    f2bf(whh[orig * 256 + (k - 512)]);
            }
        } else if (i < 1574912) {
            int i2 = i - 1572864;
            int dir = i2 >> 10;
            int n = i2 & 1023;
            int nn = n & 63, c = n >> 6;
            int orig = (nn >> 4) * 256 + c * 16 + (nn & 15);
            bc[i2] = (dir ? bb : bf)[orig];
        }
    }
    // gather-convert x rows: 8192 groups of 4 (span,rank) rows, 64 lanes each
    for (int gq = b1; gq < 8192; gq += g1) {
        int sr = gq * 4 + (tid >> 6);
        int i = tid & 63;
        int span = sr >> 3, rank = sr & 7;
        if (rank < lenb[span]) {
            int t = tok[sr];
            int b = span >> 6;
            const float4* src = (const float4*)(repr + (size_t)(b * T_ + t) * D_);
            ushort4* dst = (ushort4*)(xg + (size_t)sr * D_);
            float4 v0 = src[i * 2], v1 = src[i * 2 + 1];
            ushort4 o0, o1;
            o0.x = f2bf(v0.x); o0.y = f2bf(v0.y); o0.z = f2bf(v0.z); o0.w = f2bf(v0.w);
            o1.x = f2bf(v1.x); o1.y = f2bf(v1.y); o1.z = f2bf(v1.z); o1.w = f2bf(v1.w);
            dst[i * 2] = o0; dst[i * 2 + 1] = o1;
        }
    }
}

// ---------------- x-gate GEMM: 64 rows x 256 cols per block, K=512 ----------
// 4 xs-tiles merged: A-panel staged once per kt and reused 4x; Bs double-
// buffered (stage sub+1 while MFMA consumes sub). LDS 28KB -> 5 blocks/CU.
// Fragment-order output: xgates[((y*16+xs)*256 + tid)*16 + nt*4 + r],
// y = (dir*8+p)*64 + rbk, xs = xq*4+sub.  it = g*4 + xq.
__global__ __launch_bounds__(256) void xgk(const u16* __restrict__ xg,
                                           const u16* __restrict__ wcx,
                                           const float* __restrict__ bc,
                                           const int* __restrict__ lenb,
                                           const int* __restrict__ lists,
                                           const int* __restrict__ counts,
                                           u16* __restrict__ xgates) {
    __shared__ __align__(16) u16 As[64 * 72];
    __shared__ __align__(16) u16 Bs[2][64 * 72];
    __shared__ unsigned xoffs[64];
    int tid = threadIdx.x;
    int lane = tid & 63;
    int w16 = (tid >> 6) * 16;
    int mr = lane & 15;
    int q = lane >> 4;
    int q8 = q * 8;

    int S = 0;
#pragma unroll
    for (int pp = 0; pp < 8; ++pp) S += (counts[pp] + 63) >> 6;
    int S2 = 2 * S;

    int it = blockIdx.x;
    int g = it >> 2, xq = it & 3;
    if (g >= S2) return;
    int dir = (g >= S) ? 1 : 0;
    int gg = dir ? g - S : g;
    int p = 0;
#pragma unroll
    for (int pp = 0; pp < 7; ++pp) {
        int nbp = (counts[pp] + 63) >> 6;
        bool adv = (p == pp) && (gg >= nbp);
        if (adv) { gg -= nbp; p = pp + 1; }
    }
    int rbk = gg;
    int cnt = counts[p];
    int base = rbk * 64;

    if (tid < 64) {
        unsigned xo = 0;
        int idx = base + tid;
        if (idx < cnt) {
            int span = lists[p * 4096 + idx];
            int L = lenb[span];
            int rank = dir ? (L - 1 - p) : p;
            xo = (unsigned)(span * ML_ + rank) * D_;
        }
        xoffs[tid] = xo;
    }
    __syncthreads();

    int c0 = tid, c1 = tid + 256;
    int row0 = c0 >> 3, cc0 = (c0 & 7) * 8;
    int row1 = c1 >> 3, cc1 = (c1 & 7) * 8;
    const u16* wb = wcx + (size_t)dir * 1024 * 512;
    // per-thread B source rows for each sub-tile (n = xq*256 + sub*64 + row)
    int nbase = xq * 256;

    f4 acc[16];
    f4 zed = {0.f, 0.f, 0.f, 0.f};
#pragma unroll
    for (int i = 0; i < 16; ++i) acc[i] = zed;

    for (int kt = 0; kt < 8; ++kt) {
        // stage A (64x64) and Bs[0] <- sub 0
        *(uint4*)&As[row0 * 72 + cc0] = *(const uint4*)(xg + xoffs[row0] + kt * 64 + cc0);
        *(uint4*)&As[row1 * 72 + cc1] = *(const uint4*)(xg + xoffs[row1] + kt * 64 + cc1);
        *(uint4*)&Bs[0][row0 * 72 + cc0] =
            *(const uint4*)(wb + (size_t)(nbase + row0) * 512 + kt * 64 + cc0);
        *(uint4*)&Bs[0][row1 * 72 + cc1] =
            *(const uint4*)(wb + (size_t)(nbase + row1) * 512 + kt * 64 + cc1);
        __syncthreads();
#pragma unroll
        for (int sub = 0; sub < 4; ++sub) {
            if (sub < 3) {   // stage next sub-tile into the other buffer
                int nb = nbase + (sub + 1) * 64;
                *(uint4*)&Bs[(sub + 1) & 1][row0 * 72 + cc0] =
                    *(const uint4*)(wb + (size_t)(nb + row0) * 512 + kt * 64 + cc0);
                *(uint4*)&Bs[(sub + 1) & 1][row1 * 72 + cc1] =
                    *(const uint4*)(wb + (size_t)(nb + row1) * 512 + kt * 64 + cc1);
            }
#pragma unroll
            for (int kk = 0; kk < 64; kk += 32) {
                bf8 af = *(const bf8*)&As[(w16 + mr) * 72 + kk + q8];
#pragma unroll
                for (int nt = 0; nt < 4; ++nt) {
                    bf8 bg = *(const bf8*)&Bs[sub & 1][(nt * 16 + mr) * 72 + kk + q8];
                    acc[sub * 4 + nt] =
                        __builtin_amdgcn_mfma_f32_16x16x32_bf16(af, bg, acc[sub * 4 + nt],
                                                                0, 0, 0);
                }
            }
            __syncthreads();
        }
    }

    int y = (dir * 8 + p) * 64 + rbk;
#pragma unroll
    for (int sub = 0; sub < 4; ++sub) {
        int xs = xq * 4 + sub;
        u16 tmp[16];
#pragma unroll
        for (int nt = 0; nt < 4; ++nt)
#pragma unroll
            for (int r = 0; r < 4; ++r) {
                int n = xs * 64 + nt * 16 + mr;
                tmp[nt * 4 + r] = f2bf(acc[sub * 4 + nt][r] + bc[dir * 1024 + n]);
            }
        size_t off = ((size_t)(y * 16 + xs) * 256 + tid) * 16;
        *(uint4*)&xgates[off] = *(const uint4*)tmp;
        *(uint4*)&xgates[off + 8] = *(const uint4*)(tmp + 8);
    }
}

// ---------------- step 0: pure pointwise (h0=0, c0=0) -----------------------
// STORES cbuf/h/pooled (no zero-init pass needed anywhere).
__global__ __launch_bounds__(256) void p0k(const u16* __restrict__ xgates,
                                           const int* __restrict__ lists,
                                           const int* __restrict__ counts,
                                           float* __restrict__ cbuf,
                                           u16* __restrict__ hout,
                                           float* __restrict__ pooled) {
    __shared__ int spans_s[64];
    int tid = threadIdx.x;
    int lane = tid & 63;
    int w16 = (tid >> 6) * 16;
    int mr = lane & 15;
    int q = lane >> 4;
    int cnt = counts[0];
    int nb0 = (cnt + 63) >> 6;
    int it = blockIdx.x;
    if (it >= 2 * nb0) return;
    int dir = it / nb0;
    int rbk = it - dir * nb0;
    int base = rbk * 64;
    if (tid < 64) {
        int span = 0;
        int idx = base + tid;
        if (idx < cnt) span = lists[idx];
        spans_s[tid] = span;
    }
    __syncthreads();
    int y = dir * 512 + rbk;
    for (int xs = 0; xs < 16; ++xs) {
        u16 tmp[16];
        const uint4* s = (const uint4*)(xgates + ((size_t)(y * 16 + xs) * 256 + tid) * 16);
        ((uint4*)tmp)[0] = s[0];
        ((uint4*)tmp)[1] = s[1];
#pragma unroll
        for (int r = 0; r < 4; ++r) {
            int m = w16 + q * 4 + r;
            if (base + m < cnt) {
                int span = spans_s[m];
                int j = xs * 16 + mr;
                float gi = bf2f(tmp[0 + r]);
                float gg = bf2f(tmp[8 + r]);
                float go = bf2f(tmp[12 + r]);
                float cn = sigm(gi) * tanhf(gg);
                float h = sigm(go) * tanhf(cn);
                int si = (dir * 4096 + span) * H_ + j;
                cbuf[si] = cn;
                hout[si] = f2bf(h);
                pooled[span * 512 + dir * H_ + j] = h;   // store, not +=
            }
        }
    }
}

// ---------------- step p>=1: h@Whh GEMM (K=256) + LSTM pointwise ------------
// acc init from fragment-order xgates; linear block mapping.
__global__ __launch_bounds__(256) void stepk(const u16* __restrict__ xgates,
                                             const u16* __restrict__ hin,
                                             u16* __restrict__ hout,
                                             const u16* __restrict__ wch,
                                             const int* __restrict__ lists,
                                             const int* __restrict__ counts,
                                             float* __restrict__ cbuf,
                                             float* __restrict__ pooled, int p) {
    __shared__ __align__(16) u16 As[64 * 72];
    __shared__ __align__(16) u16 Bs[64 * 72];
    __shared__ unsigned hoffs[64];
    __shared__ int spans_s[64];
    int tid = threadIdx.x;
    int lane = tid & 63;
    int w16 = (tid >> 6) * 16;
    int mr = lane & 15;
    int q = lane >> 4;
    int q8 = q * 8;
    int cnt = counts[p];
    int nbp = (cnt + 63) >> 6;
    int S2 = 2 * nbp;

    int it = blockIdx.x;
    int g = it >> 4, xs = it & 15;
    if (g >= S2) return;
    int dir = (g >= nbp) ? 1 : 0;
    int rbk = dir ? g - nbp : g;
    int base = rbk * 64;

    if (tid < 64) {
        int span = 0;
        int idx = base + tid;
        if (idx < cnt) span = lists[p * 4096 + idx];
        spans_s[tid] = span;
        hoffs[tid] = (unsigned)(dir * 4096 + span) * H_;
    }
    __syncthreads();

    int n0 = xs * 64;
    const u16* wb = wch + (size_t)dir * 1024 * 256;
    int y = (dir * 8 + p) * 64 + rbk;
    u16 tmp[16];
    {
        const uint4* sx = (const uint4*)(xgates + ((size_t)(y * 16 + xs) * 256 + tid) * 16);
        ((uint4*)tmp)[0] = sx[0];
        ((uint4*)tmp)[1] = sx[1];
    }
    f4 acc[4];
#pragma unroll
    for (int nt = 0; nt < 4; ++nt)
#pragma unroll
        for (int r = 0; r < 4; ++r) acc[nt][r] = bf2f(tmp[nt * 4 + r]);

    for (int kt = 0; kt < 4; ++kt) {
#pragma unroll
        for (int i = 0; i < 2; ++i) {
            int c = tid + i * 256;
            int row = c >> 3;
            int cc = (c & 7) * 8;
            *(uint4*)&As[row * 72 + cc] =
                *(const uint4*)(hin + hoffs[row] + kt * 64 + cc);
            *(uint4*)&Bs[row * 72 + cc] =
                *(const uint4*)(wb + (size_t)(n0 + row) * 256 + kt * 64 + cc);
        }
        __syncthreads();
#pragma unroll
        for (int kk = 0; kk < 64; kk += 32) {
            bf8 af = *(const bf8*)&As[(w16 + mr) * 72 + kk + q8];
#pragma unroll
            for (int nt = 0; nt < 4; ++nt) {
                bf8 bg = *(const bf8*)&Bs[(nt * 16 + mr) * 72 + kk + q8];
                acc[nt] = __builtin_amdgcn_mfma_f32_16x16x32_bf16(af, bg, acc[nt], 0, 0, 0);
            }
        }
        __syncthreads();
    }

    // epilogue: LSTM pointwise, thread-local (nt = gate of j = xs*16+mr)
#pragma unroll
    for (int r = 0; r < 4; ++r) {
        int m = w16 + q * 4 + r;
        if (base + m < cnt) {
            int span = spans_s[m];
            int j = xs * 16 + mr;
            float gi = acc[0][r], gf = acc[1][r], gg = acc[2][r], go = acc[3][r];
            int si = (dir * 4096 + span) * H_ + j;
            float c = cbuf[si];
            float cn = sigm(gf) * c + sigm(gi) * tanhf(gg);
            float h = sigm(go) * tanhf(cn);
            cbuf[si] = cn;
            hout[si] = f2bf(h);
            pooled[span * 512 + dir * H_ + j] += h;
        }
    }
}

// ---------------- scores: [4096x512] x [512x64], len==0 rows masked ---------
__global__ __launch_bounds__(256) void scoresk(const float* __restrict__ pooled,
                                               const float* __restrict__ emb,
                                               const int* __restrict__ lenb,
                                               float* __restrict__ out) {
    __shared__ __align__(16) u16 As[64 * 72];
    __shared__ __align__(16) u16 Bs[64 * 72];
    int g = blockIdx.x;
    int tid = threadIdx.x;
    int lane = tid & 63;
    int w16 = (tid >> 6) * 16;
    int mr = lane & 15;
    int q = lane >> 4;
    int q8 = q * 8;

    f4 acc[4];
    f4 zed = {0.f, 0.f, 0.f, 0.f};
#pragma unroll
    for (int i = 0; i < 4; ++i) acc[i] = zed;

    for (int kt = 0; kt < 8; ++kt) {
#pragma unroll
        for (int i = 0; i < 2; ++i) {
            int c = tid + i * 256;
            int row = c >> 3;
            int cc = (c & 7) * 8;
            const float4* a =
                (const float4*)(pooled + (size_t)(g * 64 + row) * 512 + kt * 64 + cc);
            float4 v0 = a[0], v1 = a[1];
            ushort4 o0, o1;
            o0.x = f2bf(v0.x); o0.y = f2bf(v0.y); o0.z = f2bf(v0.z); o0.w = f2bf(v0.w);
            o1.x = f2bf(v1.x); o1.y = f2bf(v1.y); o1.z = f2bf(v1.z); o1.w = f2bf(v1.w);
            *(ushort4*)&As[row * 72 + cc] = o0;
            *(ushort4*)&As[row * 72 + cc + 4] = o1;
            const float4* b = (const float4*)(emb + (size_t)row * 512 + kt * 64 + cc);
            float4 w0 = b[0], w1 = b[1];
            ushort4 p0, p1;
            p0.x = f2bf(w0.x); p0.y = f2bf(w0.y); p0.z = f2bf(w0.z); p0.w = f2bf(w0.w);
            p1.x = f2bf(w1.x); p1.y = f2bf(w1.y); p1.z = f2bf(w1.z); p1.w = f2bf(w1.w);
            *(ushort4*)&Bs[row * 72 + cc] = p0;
            *(ushort4*)&Bs[row * 72 + cc + 4] = p1;
        }
        __syncthreads();
#pragma unroll
        for (int kk = 0; kk < 64; kk += 32) {
            bf8 af = *(const bf8*)&As[(w16 + mr) * 72 + kk + q8];
#pragma unroll
            for (int nt = 0; nt < 4; ++nt) {
                bf8 bg = *(const bf8*)&Bs[(nt * 16 + mr) * 72 + kk + q8];
                acc[nt] = __builtin_amdgcn_mfma_f32_16x16x32_bf16(af, bg, acc[nt], 0, 0, 0);
            }
        }
        __syncthreads();
    }

#pragma unroll
    for (int r = 0; r < 4; ++r) {
        int m = g * 64 + w16 + q * 4 + r;
        int ln = lenb[m];
#pragma unroll
        for (int nt = 0; nt < 4; ++nt) {
            int n = nt * 16 + mr;
            out[(size_t)m * 64 + n] = (ln > 0) ? acc[nt][r] : 0.f;
        }
    }
}

// ---------------- launch ----------------

extern "C" void kernel_launch(void* const* d_in, const int* in_sizes, int n_in,
                              void* d_out, int out_size, void* d_ws, size_t ws_size,
                              hipStream_t stream) {
    const float* lstm_repr = (const float*)d_in[0];
    const float* W_ih_f = (const float*)d_in[1];
    const float* W_hh_f = (const float*)d_in[2];
    const float* b_f    = (const float*)d_in[3];
    const float* W_ih_b = (const float*)d_in[4];
    const float* W_hh_b = (const float*)d_in[5];
    const float* b_b    = (const float*)d_in[6];
    const float* slot_emb = (const float*)d_in[7];
    const int* bio      = (const int*)d_in[8];
    float* out = (float*)d_out;

    char* ws = (char*)d_ws;
    u16*  xg     = (u16*)(ws + 0);              // 4096*8*512 bf16      =  33,554,432
    u16*  xgates = (u16*)(ws + 33554432);       // 1024*16*256*16 bf16  = 134,217,728
    u16*  wcx    = (u16*)(ws + 167772160);      // 2*1024*512 bf16      =   2,097,152
    u16*  wch    = (u16*)(ws + 169869312);      // 2*1024*256 bf16      =   1,048,576
    float* bc    = (float*)(ws + 170917888);    // 2*1024 f32           =       8,192
    int*  tok    = (int*)(ws + 170926080);      // 4096*8 i32           =     131,072
    int*  lenb   = (int*)(ws + 171057152);      // 4096 i32             =      16,384
    int*  lists  = (int*)(ws + 171073536);      // 8*4096 i32           =     131,072
    int*  counts = (int*)(ws + 171204608);      // 8 i32 (256B pad)
    float* pooled= (float*)(ws + 171204864);    // 4096*512 f32         =   8,388,608
    float* cbuf  = (float*)(ws + 179593472);    // 2*4096*256 f32       =   8,388,608
    u16*  h0     = (u16*)(ws + 187982080);      // 2*4096*256 bf16      =   4,194,304
    u16*  h1     = (u16*)(ws + 192176384);      // 2*4096*256 bf16      =   4,194,304
    // total: 196,370,688 bytes (ws = 256 MiB); no zero-init needed

    pack_spans2<<<64, 512, 0, stream>>>(bio, tok, lenb);
    prep<<<2048, 256, 0, stream>>>(W_ih_f, W_hh_f, W_ih_b, W_hh_b, b_f, b_b,
                                   wcx, wch, bc, lstm_repr, tok, lenb,
                                   lists, counts, xg);
    xgk<<<4096, 256, 0, stream>>>(xg, wcx, bc, lenb, lists, counts, xgates);
    p0k<<<128, 256, 0, stream>>>(xgates, lists, counts, cbuf, h1, pooled);
    for (int p = 1; p < 8; ++p) {
        const u16* hin = (p & 1) ? h1 : h0;
        u16* hout = (p & 1) ? h0 : h1;
        stepk<<<2048, 256, 0, stream>>>(xgates, hin, hout, wch, lists, counts,
                                        cbuf, pooled, p);
    }
    scoresk<<<64, 256, 0, stream>>>(pooled, slot_emb, lenb, out);
}

// Round 11
// 243.079 us; speedup vs baseline: 1.2539x; 1.2539x over previous
//
#include <hip/hip_runtime.h>
#include <hip/hip_bf16.h>
#include <stdint.h>

// Problem constants
#define B_ 64
#define T_ 512
#define H_ 256
#define D_ 512
#define MS_ 64
#define ML_ 8
#define NST_ 64

typedef unsigned short u16;
typedef __bf16 bf8 __attribute__((ext_vector_type(8)));
typedef float f4 __attribute__((ext_vector_type(4)));

__device__ __forceinline__ u16 f2bf(float f) {
    unsigned u = __builtin_bit_cast(unsigned, f);
    u += 0x7fffu + ((u >> 16) & 1u);   // round-to-nearest-even
    return (u16)(u >> 16);
}
__device__ __forceinline__ float bf2f(u16 v) {
    return __builtin_bit_cast(float, (unsigned)v << 16);
}
__device__ __forceinline__ float sigm(float x) { return 1.f / (1.f + __expf(-x)); }

// NOTE: LDS tiles MUST be standalone __shared__ arrays (16B-aligned), not
// struct members. struct SB (align 4) defeated b128 LDS vectorization:
// conflicts 5.3e6 -> 4.5e7, xgate 48us -> 117us (rounds 5-8 regression).
// NOTE: tile-merging (4 n-tiles/block) tested twice (r3, r10): FETCH drops
// but occupancy/barrier cost dominates -> slower. 64x64/block is optimal.

// ---------------- pack_spans (1 block/sentence, 1 thread/token) -------------
__global__ __launch_bounds__(512) void pack_spans2(const int* __restrict__ bio,
                                                   int* __restrict__ tok,
                                                   int* __restrict__ lenb) {
    __shared__ int wsum[8];
    __shared__ int start_s[64];
    __shared__ int len_s[64];
    int b = blockIdx.x;
    int t = threadIdx.x;
    int lane = t & 63, w = t >> 6;
    int v = bio[b * T_ + t];
    int bm = (v == 1);
    int im = (v == 2);
    if (t < 64) len_s[t] = 0;

    int x = bm;
#pragma unroll
    for (int off = 1; off < 64; off <<= 1) {
        int y = __shfl_up(x, off, 64);
        if (lane >= off) x += y;
    }
    if (lane == 63) wsum[w] = x;
    __syncthreads();
    int wof = 0;
    for (int i = 0; i < w; ++i) wof += wsum[i];
    int sid = x + wof - 1;
    int valid = ((bm | im) && sid >= 0) ? 1 : 0;
    __syncthreads();

    x = valid;
#pragma unroll
    for (int off = 1; off < 64; off <<= 1) {
        int y = __shfl_up(x, off, 64);
        if (lane >= off) x += y;
    }
    if (lane == 63) wsum[w] = x;
    __syncthreads();
    wof = 0;
    for (int i = 0; i < w; ++i) wof += wsum[i];
    int cs = x + wof;

    if (bm && sid < MS_) start_s[sid] = cs;
    __syncthreads();

    if (valid && sid < MS_) {
        int rank = cs - start_s[sid];
        if (rank < ML_) {
            tok[(b * MS_ + sid) * ML_ + rank] = t;
            atomicAdd(&len_s[sid], 1);
        }
    }
    __syncthreads();
    if (t < 64) lenb[b * MS_ + t] = len_s[t];
}

// ---------------- prep: block0 = lists; others = weight reorder + gather ----
// Gate-interleaved column reorder: col n: gate = (n&63)>>4, j = (n>>6)*16+(n&15),
// orig_row = gate*256 + j.  wcx[dir][n][0:512], wch[dir][n][0:256], bc[dir][n].
__global__ __launch_bounds__(256) void prep(
        const float* __restrict__ wihf, const float* __restrict__ whhf,
        const float* __restrict__ wihb, const float* __restrict__ whhb,
        const float* __restrict__ bf, const float* __restrict__ bb,
        u16* __restrict__ wcx, u16* __restrict__ wch, float* __restrict__ bc,
        const float* __restrict__ repr, const int* __restrict__ tok,
        const int* __restrict__ lenb,
        int* __restrict__ lists, int* __restrict__ counts, u16* __restrict__ xg) {
    int bid = blockIdx.x, gsz = gridDim.x, tid = threadIdx.x;
    if (bid == 0) {
        // per-step compacted active-span lists; counts[p] = #spans with len > p
        __shared__ int wsum[4];
        int lane = tid & 63, w = tid >> 6;
        int len[16];
#pragma unroll
        for (int i = 0; i < 16; ++i) len[i] = lenb[tid * 16 + i];
        for (int p = 0; p < ML_; ++p) {
            int c = 0;
#pragma unroll
            for (int i = 0; i < 16; ++i) c += (len[i] > p) ? 1 : 0;
            int x = c;
#pragma unroll
            for (int off = 1; off < 64; off <<= 1) {
                int y = __shfl_up(x, off, 64);
                if (lane >= off) x += y;
            }
            if (lane == 63) wsum[w] = x;
            __syncthreads();
            int wof = 0;
            for (int i = 0; i < w; ++i) wof += wsum[i];
            int pos = wof + x - c;
#pragma unroll
            for (int i = 0; i < 16; ++i)
                if (len[i] > p) lists[p * 4096 + pos++] = tid * 16 + i;
            if (tid == 255) counts[p] = pos;
            __syncthreads();
        }
        return;
    }
    int b1 = bid - 1, g1 = gsz - 1;
    // weight reorder: 6152 chunks x 256 elems (2*1024*768 weights + 2048 bias)
    for (int ch = b1; ch < 6152; ch += g1) {
        int i = ch * 256 + tid;
        if (i < 1572864) {
            int dir = i / 786432;
            int rem = i - dir * 786432;
            int n = rem / 768;
            int k = rem - n * 768;
            int nn = n & 63, c = n >> 6;
            int orig = (nn >> 4) * 256 + c * 16 + (nn & 15);
            if (k < 512) {
                const float* wih = dir ? wihb : wihf;
                wcx[((size_t)dir * 1024 + n) * 512 + k] = f2bf(wih[orig * 512 + k]);
            } else {
                const float* whh = dir ? whhb : whhf;
                wch[((size_t)dir * 1024 + n) * 256 + (k - 512)] =
                    f2bf(whh[orig * 256 + (k - 512)]);
            }
        } else if (i < 1574912) {
            int i2 = i - 1572864;
            int dir = i2 >> 10;
            int n = i2 & 1023;
            int nn = n & 63, c = n >> 6;
            int orig = (nn >> 4) * 256 + c * 16 + (nn & 15);
            bc[i2] = (dir ? bb : bf)[orig];
        }
    }
    // gather-convert x rows: 8192 groups of 4 (span,rank) rows, 64 lanes each
    for (int gq = b1; gq < 8192; gq += g1) {
        int sr = gq * 4 + (tid >> 6);
        int i = tid & 63;
        int span = sr >> 3, rank = sr & 7;
        if (rank < lenb[span]) {
            int t = tok[sr];
            int b = span >> 6;
            const float4* src = (const float4*)(repr + (size_t)(b * T_ + t) * D_);
            ushort4* dst = (ushort4*)(xg + (size_t)sr * D_);
            float4 v0 = src[i * 2], v1 = src[i * 2 + 1];
            ushort4 o0, o1;
            o0.x = f2bf(v0.x); o0.y = f2bf(v0.y); o0.z = f2bf(v0.z); o0.w = f2bf(v0.w);
            o1.x = f2bf(v1.x); o1.y = f2bf(v1.y); o1.z = f2bf(v1.z); o1.w = f2bf(v1.w);
            dst[i * 2] = o0; dst[i * 2 + 1] = o1;
        }
    }
}

// ---------------- x-gate GEMM: 64 rows x 64 cols, K=512 ---------------------
// Fragment-order output (p>=1): xgates[((y*16+xs)*256 + tid)*16 + nt*4 + r],
// y = (dir*8+p)*64 + rbk.  For p==0: fused LSTM pointwise epilogue (h0=c0=0)
// writes cbuf/h1/pooled directly from the f32 accumulator; no xgates store.
// XCD-clustered mapping: it = qq*128 + xs*8 + r8, g = qq*8 + r8 -> the 16 xs
// of a group share it%8 (same XCD) -> A-panel is an L2 hit (FETCH 64->~16MB).
__global__ __launch_bounds__(256) void xgk(const u16* __restrict__ xg,
                                           const u16* __restrict__ wcx,
                                           const float* __restrict__ bc,
                                           const int* __restrict__ lenb,
                                           const int* __restrict__ lists,
                                           const int* __restrict__ counts,
                                           u16* __restrict__ xgates,
                                           float* __restrict__ cbuf,
                                           u16* __restrict__ h1,
                                           float* __restrict__ pooled) {
    __shared__ __align__(16) u16 As[64 * 72];
    __shared__ __align__(16) u16 Bs[64 * 72];
    __shared__ unsigned xoffs[64];
    __shared__ int spans_s[64];
    int tid = threadIdx.x;
    int lane = tid & 63;
    int w16 = (tid >> 6) * 16;
    int mr = lane & 15;
    int q = lane >> 4;
    int q8 = q * 8;

    int S = 0;
#pragma unroll
    for (int pp = 0; pp < 8; ++pp) S += (counts[pp] + 63) >> 6;
    int S2 = 2 * S;

    int it = blockIdx.x;
    int qq = it >> 7, rem = it & 127, xs = rem >> 3, r8 = rem & 7;
    int g = qq * 8 + r8;
    if (g >= S2) return;
    int dir = (g >= S) ? 1 : 0;
    int gg = dir ? g - S : g;
    int p = 0;
#pragma unroll
    for (int pp = 0; pp < 7; ++pp) {
        int nbp = (counts[pp] + 63) >> 6;
        bool adv = (p == pp) && (gg >= nbp);
        if (adv) { gg -= nbp; p = pp + 1; }
    }
    int rbk = gg;
    int cnt = counts[p];
    int base = rbk * 64;

    if (tid < 64) {
        unsigned xo = 0;
        int span = 0;
        int idx = base + tid;
        if (idx < cnt) {
            span = lists[p * 4096 + idx];
            int L = lenb[span];
            int rank = dir ? (L - 1 - p) : p;
            xo = (unsigned)(span * ML_ + rank) * D_;
        }
        xoffs[tid] = xo;
        spans_s[tid] = span;
    }
    __syncthreads();

    int n0 = xs * 64;
    const u16* wb = wcx + (size_t)dir * 1024 * 512;
    f4 acc[4];
    f4 zed = {0.f, 0.f, 0.f, 0.f};
#pragma unroll
    for (int i = 0; i < 4; ++i) acc[i] = zed;

    for (int kt = 0; kt < 8; ++kt) {
#pragma unroll
        for (int i = 0; i < 2; ++i) {
            int c = tid + i * 256;
            int row = c >> 3;
            int cc = (c & 7) * 8;
            *(uint4*)&As[row * 72 + cc] =
                *(const uint4*)(xg + xoffs[row] + kt * 64 + cc);
            *(uint4*)&Bs[row * 72 + cc] =
                *(const uint4*)(wb + (size_t)(n0 + row) * 512 + kt * 64 + cc);
        }
        __syncthreads();
#pragma unroll
        for (int kk = 0; kk < 64; kk += 32) {
            bf8 af = *(const bf8*)&As[(w16 + mr) * 72 + kk + q8];
#pragma unroll
            for (int nt = 0; nt < 4; ++nt) {
                bf8 bg = *(const bf8*)&Bs[(nt * 16 + mr) * 72 + kk + q8];
                acc[nt] = __builtin_amdgcn_mfma_f32_16x16x32_bf16(af, bg, acc[nt], 0, 0, 0);
            }
        }
        __syncthreads();
    }

    // + bias (f32)
    float tf[16];
#pragma unroll
    for (int nt = 0; nt < 4; ++nt)
#pragma unroll
        for (int r = 0; r < 4; ++r) {
            int n = n0 + nt * 16 + mr;
            tf[nt * 4 + r] = acc[nt][r] + bc[dir * 1024 + n];
        }

    if (p == 0) {
        // fused step-0 LSTM pointwise: c0 = 0, h0 = 0 -> STORES (no zero-init)
        int j = xs * 16 + mr;
#pragma unroll
        for (int r = 0; r < 4; ++r) {
            int m = w16 + q * 4 + r;
            if (base + m < cnt) {
                int span = spans_s[m];
                float gi = tf[0 + r], gg2 = tf[8 + r], go = tf[12 + r];
                float cn = sigm(gi) * tanhf(gg2);
                float h = sigm(go) * tanhf(cn);
                int si = (dir * 4096 + span) * H_ + j;
                cbuf[si] = cn;
                h1[si] = f2bf(h);
                pooled[span * 512 + dir * H_ + j] = h;   // store, not +=
            }
        }
    } else {
        int y = (dir * 8 + p) * 64 + rbk;
        u16 tmp[16];
#pragma unroll
        for (int i = 0; i < 16; ++i) tmp[i] = f2bf(tf[i]);
        size_t off = ((size_t)(y * 16 + xs) * 256 + tid) * 16;
        *(uint4*)&xgates[off] = *(const uint4*)tmp;
        *(uint4*)&xgates[off + 8] = *(const uint4*)(tmp + 8);
    }
}

// ---------------- step p>=1: h@Whh GEMM (K=256) + LSTM pointwise ------------
// acc init from fragment-order xgates; linear block mapping.
__global__ __launch_bounds__(256) void stepk(const u16* __restrict__ xgates,
                                             const u16* __restrict__ hin,
                                             u16* __restrict__ hout,
                                             const u16* __restrict__ wch,
                                             const int* __restrict__ lists,
                                             const int* __restrict__ counts,
                                             float* __restrict__ cbuf,
                                             float* __restrict__ pooled, int p) {
    __shared__ __align__(16) u16 As[64 * 72];
    __shared__ __align__(16) u16 Bs[64 * 72];
    __shared__ unsigned hoffs[64];
    __shared__ int spans_s[64];
    int tid = threadIdx.x;
    int lane = tid & 63;
    int w16 = (tid >> 6) * 16;
    int mr = lane & 15;
    int q = lane >> 4;
    int q8 = q * 8;
    int cnt = counts[p];
    int nbp = (cnt + 63) >> 6;
    int S2 = 2 * nbp;

    int it = blockIdx.x;
    int g = it >> 4, xs = it & 15;
    if (g >= S2) return;
    int dir = (g >= nbp) ? 1 : 0;
    int rbk = dir ? g - nbp : g;
    int base = rbk * 64;

    if (tid < 64) {
        int span = 0;
        int idx = base + tid;
        if (idx < cnt) span = lists[p * 4096 + idx];
        spans_s[tid] = span;
        hoffs[tid] = (unsigned)(dir * 4096 + span) * H_;
    }
    __syncthreads();

    int n0 = xs * 64;
    const u16* wb = wch + (size_t)dir * 1024 * 256;
    int y = (dir * 8 + p) * 64 + rbk;
    u16 tmp[16];
    {
        const uint4* sx = (const uint4*)(xgates + ((size_t)(y * 16 + xs) * 256 + tid) * 16);
        ((uint4*)tmp)[0] = sx[0];
        ((uint4*)tmp)[1] = sx[1];
    }
    f4 acc[4];
#pragma unroll
    for (int nt = 0; nt < 4; ++nt)
#pragma unroll
        for (int r = 0; r < 4; ++r) acc[nt][r] = bf2f(tmp[nt * 4 + r]);

    for (int kt = 0; kt < 4; ++kt) {
#pragma unroll
        for (int i = 0; i < 2; ++i) {
            int c = tid + i * 256;
            int row = c >> 3;
            int cc = (c & 7) * 8;
            *(uint4*)&As[row * 72 + cc] =
                *(const uint4*)(hin + hoffs[row] + kt * 64 + cc);
            *(uint4*)&Bs[row * 72 + cc] =
                *(const uint4*)(wb + (size_t)(n0 + row) * 256 + kt * 64 + cc);
        }
        __syncthreads();
#pragma unroll
        for (int kk = 0; kk < 64; kk += 32) {
            bf8 af = *(const bf8*)&As[(w16 + mr) * 72 + kk + q8];
#pragma unroll
            for (int nt = 0; nt < 4; ++nt) {
                bf8 bg = *(const bf8*)&Bs[(nt * 16 + mr) * 72 + kk + q8];
                acc[nt] = __builtin_amdgcn_mfma_f32_16x16x32_bf16(af, bg, acc[nt], 0, 0, 0);
            }
        }
        __syncthreads();
    }

    // epilogue: LSTM pointwise, thread-local (nt = gate of j = xs*16+mr)
#pragma unroll
    for (int r = 0; r < 4; ++r) {
        int m = w16 + q * 4 + r;
        if (base + m < cnt) {
            int span = spans_s[m];
            int j = xs * 16 + mr;
            float gi = acc[0][r], gf = acc[1][r], gg = acc[2][r], go = acc[3][r];
            int si = (dir * 4096 + span) * H_ + j;
            float c = cbuf[si];
            float cn = sigm(gf) * c + sigm(gi) * tanhf(gg);
            float h = sigm(go) * tanhf(cn);
            cbuf[si] = cn;
            hout[si] = f2bf(h);
            pooled[span * 512 + dir * H_ + j] += h;
        }
    }
}

// ---------------- scores: [4096x512] x [512x64], len==0 rows masked ---------
__global__ __launch_bounds__(256) void scoresk(const float* __restrict__ pooled,
                                               const float* __restrict__ emb,
                                               const int* __restrict__ lenb,
                                               float* __restrict__ out) {
    __shared__ __align__(16) u16 As[64 * 72];
    __shared__ __align__(16) u16 Bs[64 * 72];
    int g = blockIdx.x;
    int tid = threadIdx.x;
    int lane = tid & 63;
    int w16 = (tid >> 6) * 16;
    int mr = lane & 15;
    int q = lane >> 4;
    int q8 = q * 8;

    f4 acc[4];
    f4 zed = {0.f, 0.f, 0.f, 0.f};
#pragma unroll
    for (int i = 0; i < 4; ++i) acc[i] = zed;

    for (int kt = 0; kt < 8; ++kt) {
#pragma unroll
        for (int i = 0; i < 2; ++i) {
            int c = tid + i * 256;
            int row = c >> 3;
            int cc = (c & 7) * 8;
            const float4* a =
                (const float4*)(pooled + (size_t)(g * 64 + row) * 512 + kt * 64 + cc);
            float4 v0 = a[0], v1 = a[1];
            ushort4 o0, o1;
            o0.x = f2bf(v0.x); o0.y = f2bf(v0.y); o0.z = f2bf(v0.z); o0.w = f2bf(v0.w);
            o1.x = f2bf(v1.x); o1.y = f2bf(v1.y); o1.z = f2bf(v1.z); o1.w = f2bf(v1.w);
            *(ushort4*)&As[row * 72 + cc] = o0;
            *(ushort4*)&As[row * 72 + cc + 4] = o1;
            const float4* b = (const float4*)(emb + (size_t)row * 512 + kt * 64 + cc);
            float4 w0 = b[0], w1 = b[1];
            ushort4 p0, p1;
            p0.x = f2bf(w0.x); p0.y = f2bf(w0.y); p0.z = f2bf(w0.z); p0.w = f2bf(w0.w);
            p1.x = f2bf(w1.x); p1.y = f2bf(w1.y); p1.z = f2bf(w1.z); p1.w = f2bf(w1.w);
            *(ushort4*)&Bs[row * 72 + cc] = p0;
            *(ushort4*)&Bs[row * 72 + cc + 4] = p1;
        }
        __syncthreads();
#pragma unroll
        for (int kk = 0; kk < 64; kk += 32) {
            bf8 af = *(const bf8*)&As[(w16 + mr) * 72 + kk + q8];
#pragma unroll
            for (int nt = 0; nt < 4; ++nt) {
                bf8 bg = *(const bf8*)&Bs[(nt * 16 + mr) * 72 + kk + q8];
                acc[nt] = __builtin_amdgcn_mfma_f32_16x16x32_bf16(af, bg, acc[nt], 0, 0, 0);
            }
        }
        __syncthreads();
    }

#pragma unroll
    for (int r = 0; r < 4; ++r) {
        int m = g * 64 + w16 + q * 4 + r;
        int ln = lenb[m];
#pragma unroll
        for (int nt = 0; nt < 4; ++nt) {
            int n = nt * 16 + mr;
            out[(size_t)m * 64 + n] = (ln > 0) ? acc[nt][r] : 0.f;
        }
    }
}

// ---------------- launch ----------------

extern "C" void kernel_launch(void* const* d_in, const int* in_sizes, int n_in,
                              void* d_out, int out_size, void* d_ws, size_t ws_size,
                              hipStream_t stream) {
    const float* lstm_repr = (const float*)d_in[0];
    const float* W_ih_f = (const float*)d_in[1];
    const float* W_hh_f = (const float*)d_in[2];
    const float* b_f    = (const float*)d_in[3];
    const float* W_ih_b = (const float*)d_in[4];
    const float* W_hh_b = (const float*)d_in[5];
    const float* b_b    = (const float*)d_in[6];
    const float* slot_emb = (const float*)d_in[7];
    const int* bio      = (const int*)d_in[8];
    float* out = (float*)d_out;

    char* ws = (char*)d_ws;
    u16*  xg     = (u16*)(ws + 0);              // 4096*8*512 bf16      =  33,554,432
    u16*  xgates = (u16*)(ws + 33554432);       // 1024*16*256*16 bf16  = 134,217,728
    u16*  wcx    = (u16*)(ws + 167772160);      // 2*1024*512 bf16      =   2,097,152
    u16*  wch    = (u16*)(ws + 169869312);      // 2*1024*256 bf16      =   1,048,576
    float* bc    = (float*)(ws + 170917888);    // 2*1024 f32           =       8,192
    int*  tok    = (int*)(ws + 170926080);      // 4096*8 i32           =     131,072
    int*  lenb   = (int*)(ws + 171057152);      // 4096 i32             =      16,384
    int*  lists  = (int*)(ws + 171073536);      // 8*4096 i32           =     131,072
    int*  counts = (int*)(ws + 171204608);      // 8 i32 (256B pad)
    float* pooled= (float*)(ws + 171204864);    // 4096*512 f32         =   8,388,608
    float* cbuf  = (float*)(ws + 179593472);    // 2*4096*256 f32       =   8,388,608
    u16*  h0     = (u16*)(ws + 187982080);      // 2*4096*256 bf16      =   4,194,304
    u16*  h1     = (u16*)(ws + 192176384);      // 2*4096*256 bf16      =   4,194,304
    // total: 196,370,688 bytes (ws = 256 MiB); no zero-init needed

    pack_spans2<<<64, 512, 0, stream>>>(bio, tok, lenb);
    prep<<<2048, 256, 0, stream>>>(W_ih_f, W_hh_f, W_ih_b, W_hh_b, b_f, b_b,
                                   wcx, wch, bc, lstm_repr, tok, lenb,
                                   lists, counts, xg);
    // xgk: x-gates for p>=1 + fused step-0 pointwise (writes cbuf/h1/pooled)
    xgk<<<16384, 256, 0, stream>>>(xg, wcx, bc, lenb, lists, counts, xgates,
                                   cbuf, h1, pooled);
    for (int p = 1; p < 8; ++p) {
        const u16* hin = (p & 1) ? h1 : h0;
        u16* hout = (p & 1) ? h0 : h1;
        stepk<<<2048, 256, 0, stream>>>(xgates, hin, hout, wch, lists, counts,
                                        cbuf, pooled, p);
    }
    scoresk<<<64, 256, 0, stream>>>(pooled, slot_emb, lenb, out);
}